// Round 1
// baseline (1094.340 us; speedup 1.0000x reference)
//
#include <hip/hip_runtime.h>

typedef _Float16 half_t;
typedef __attribute__((ext_vector_type(8))) _Float16 half8;
typedef __attribute__((ext_vector_type(4))) _Float16 half4v;
typedef __attribute__((ext_vector_type(4))) float f32x4;

#define MFMA16(a,b,c) __builtin_amdgcn_mfma_f32_16x16x32_f16((a),(b),(c),0,0,0)

__device__ __forceinline__ void gld_lds16(const half_t* g, half_t* l){
    __builtin_amdgcn_global_load_lds((__attribute__((address_space(1))) void*)(g),
                                     (__attribute__((address_space(3))) void*)(l), 16, 0, 0);
}

// ---------------- fp32 -> fp16 convert ----------------
__global__ __launch_bounds__(256) void cvt_k(const float* __restrict__ s, half_t* __restrict__ d, int n4){
    int i = blockIdx.x * 256 + threadIdx.x;
    if (i < n4){
        float4 v = ((const float4*)s)[i];
        half4v h = { (half_t)v.x, (half_t)v.y, (half_t)v.z, (half_t)v.w };
        ((half4v*)d)[i] = h;
    }
}

// ---------------- NT GEMM: C[m,n] = sum_k A[m,k]*B[n,k], M rows of A, B row-major N x K ----------------
// kind 0: QKV fused (grid.y = 48; which = bn>>4: 0->Qw [b,h,s,d], 1->Kw [b,h,s,d], 2->Vt [b,h,d,s])
// kind 1: O-proj, fp32 out row-major [m][n]
__global__ __launch_bounds__(256) void gemm_nt(const half_t* __restrict__ A, const half_t* __restrict__ B,
                                               half_t* __restrict__ Qw, half_t* __restrict__ Kw,
                                               half_t* __restrict__ Vt, float* __restrict__ Co, int kind){
    const int tid  = threadIdx.x;
    const int lane = tid & 63;
    const int wav  = tid >> 6;
    const int wm   = (wav >> 1) * 64;
    const int wn   = (wav & 1) * 64;
    const int bm   = blockIdx.x;
    const int bn   = blockIdx.y;
    const int KD   = 2048;

    __shared__ __align__(16) half_t As[128*64];
    __shared__ __align__(16) half_t Bs[128*64];

    f32x4 acc[4][4] = {};

    const half_t* Ab = A + (size_t)bm * 128 * KD;
    const half_t* Bb = B + (size_t)bn * 128 * KD;

    for (int k0 = 0; k0 < KD; k0 += 64){
#pragma unroll
        for (int i = 0; i < 4; i++){
            int c = tid + i*256;
            gld_lds16(Ab + (size_t)(c>>3)*KD + k0 + (c&7)*8, As + c*8);
        }
#pragma unroll
        for (int i = 0; i < 4; i++){
            int c = tid + i*256;
            gld_lds16(Bb + (size_t)(c>>3)*KD + k0 + (c&7)*8, Bs + c*8);
        }
        __syncthreads();
#pragma unroll
        for (int ks = 0; ks < 2; ks++){
            const int kb = ks*32 + (lane>>4)*8;
            half8 af[4], bf[4];
#pragma unroll
            for (int mi = 0; mi < 4; mi++) af[mi] = *(const half8*)(As + (wm + mi*16 + (lane&15))*64 + kb);
#pragma unroll
            for (int ni = 0; ni < 4; ni++) bf[ni] = *(const half8*)(Bs + (wn + ni*16 + (lane&15))*64 + kb);
#pragma unroll
            for (int mi = 0; mi < 4; mi++)
#pragma unroll
                for (int ni = 0; ni < 4; ni++)
                    acc[mi][ni] = MFMA16(af[mi], bf[ni], acc[mi][ni]);
        }
        __syncthreads();
    }

    const int rbase = wm + (lane>>4)*4;   // + mi*16 + r
    const int cbase = wn + (lane&15);     // + ni*16

    if (kind == 0){
        const int which = bn >> 4;
        const int nb = (bn & 15) * 128;
        if (which < 2){
            half_t* dst = which ? Kw : Qw;
#pragma unroll
            for (int mi = 0; mi < 4; mi++)
#pragma unroll
                for (int ni = 0; ni < 4; ni++)
#pragma unroll
                    for (int r = 0; r < 4; r++){
                        int m = bm*128 + rbase + mi*16 + r;
                        int n = nb + cbase + ni*16;
                        dst[(((size_t)(m>>11)*16 + (n>>7))*2048 + (m&2047))*128 + (n&127)] = (half_t)acc[mi][ni][r];
                    }
        } else {
#pragma unroll
            for (int mi = 0; mi < 4; mi++)
#pragma unroll
                for (int ni = 0; ni < 4; ni++){
                    int m0 = bm*128 + rbase + mi*16;
                    int n  = nb + cbase + ni*16;
                    half4v h = {(half_t)acc[mi][ni][0], (half_t)acc[mi][ni][1],
                                (half_t)acc[mi][ni][2], (half_t)acc[mi][ni][3]};
                    *(half4v*)(Vt + (((size_t)(m0>>11)*16 + (n>>7))*128 + (n&127))*2048 + (m0&2047)) = h;
                }
        }
    } else {
#pragma unroll
        for (int mi = 0; mi < 4; mi++)
#pragma unroll
            for (int ni = 0; ni < 4; ni++)
#pragma unroll
                for (int r = 0; r < 4; r++){
                    int m = bm*128 + rbase + mi*16 + r;
                    int n = bn*128 + cbase + ni*16;
                    Co[(size_t)m*2048 + n] = acc[mi][ni][r];
                }
    }
}

// ---------------- RoPE in-place on Q and K ([b*16+h][s][128] fp16) ----------------
__global__ __launch_bounds__(256) void rope_k(half_t* __restrict__ Qw, half_t* __restrict__ Kw,
                                              const float* __restrict__ cs, const float* __restrict__ sn){
    int t  = blockIdx.x * 256 + threadIdx.x;   // 64*2048*64 total
    int d  = t & 63;
    int s  = (t >> 6) & 2047;
    int bh = t >> 17;
    float c  = cs[s*64 + d];
    float si = sn[s*64 + d];
    size_t base = ((size_t)bh*2048 + s)*128 + d;
    float q1 = (float)Qw[base], q2 = (float)Qw[base+64];
    Qw[base]    = (half_t)(q1*c - q2*si);
    Qw[base+64] = (half_t)(q1*si + q2*c);
    float k1 = (float)Kw[base], k2 = (float)Kw[base+64];
    Kw[base]    = (half_t)(k1*c - k2*si);
    Kw[base+64] = (half_t)(k1*si + k2*c);
}

// ---------------- Flash attention: Q[bh][s][128], K[bh][s][128], Vt[bh][128][s] -> AO[(b,s)][h*128+d] ----------------
__global__ __launch_bounds__(256) void attn_k(const half_t* __restrict__ Q, const half_t* __restrict__ K,
                                              const half_t* __restrict__ Vt, half_t* __restrict__ AO){
    const int tid  = threadIdx.x;
    const int lane = tid & 63;
    const int wav  = tid >> 6;
    const int qt   = blockIdx.x;   // 16 q-tiles of 128
    const int bh   = blockIdx.y;   // 64

    __shared__ __align__(16) half_t Ks[64*128];   // [key][d]
    __shared__ __align__(16) half_t Vs[128*64];   // [d][key]
    __shared__ __align__(16) half_t Ps[128*72];   // [q][key] padded +8

    // Q fragments in registers (wave owns 32 q rows)
    const half_t* Qb = Q + ((size_t)bh*2048 + qt*128 + wav*32)*128;
    half8 aq[2][4];
#pragma unroll
    for (int mi = 0; mi < 2; mi++)
#pragma unroll
        for (int ks = 0; ks < 4; ks++)
            aq[mi][ks] = *(const half8*)(Qb + (mi*16 + (lane&15))*128 + ks*32 + (lane>>4)*8);

    f32x4 oacc[2][8] = {};
    float mr[2][4], lr[2][4];
#pragma unroll
    for (int mi = 0; mi < 2; mi++)
#pragma unroll
        for (int r = 0; r < 4; r++){ mr[mi][r] = -1e30f; lr[mi][r] = 0.0f; }

    const float SSC = 0.08838834764831845f * 1.4426950408889634f;  // 1/sqrt(128) * log2(e)

    for (int kt = 0; kt < 32; kt++){
        const half_t* Kb = K  + ((size_t)bh*2048 + kt*64)*128;
        const half_t* Vb = Vt + (size_t)bh*128*2048 + kt*64;
        __syncthreads();
#pragma unroll
        for (int i = 0; i < 4; i++){
            int c = tid + i*256;
            gld_lds16(Kb + (c>>4)*128 + (c&15)*8, Ks + c*8);
        }
#pragma unroll
        for (int i = 0; i < 4; i++){
            int c = tid + i*256;
            gld_lds16(Vb + (size_t)(c>>3)*2048 + (c&7)*8, Vs + c*8);
        }
        __syncthreads();

        // S = Q @ K^T
        f32x4 sacc[2][4] = {};
#pragma unroll
        for (int ks = 0; ks < 4; ks++){
            const int kb = ks*32 + (lane>>4)*8;
            half8 bf[4];
#pragma unroll
            for (int ni = 0; ni < 4; ni++) bf[ni] = *(const half8*)(Ks + (ni*16 + (lane&15))*128 + kb);
#pragma unroll
            for (int mi = 0; mi < 2; mi++)
#pragma unroll
                for (int ni = 0; ni < 4; ni++)
                    sacc[mi][ni] = MFMA16(aq[mi][ks], bf[ni], sacc[mi][ni]);
        }

        // online softmax (rows live within the 16-lane group)
        float al[2][4];
#pragma unroll
        for (int mi = 0; mi < 2; mi++)
#pragma unroll
            for (int r = 0; r < 4; r++){
                float v = sacc[mi][0][r];
                v = fmaxf(v, sacc[mi][1][r]); v = fmaxf(v, sacc[mi][2][r]); v = fmaxf(v, sacc[mi][3][r]);
                v = fmaxf(v, __shfl_xor(v, 1)); v = fmaxf(v, __shfl_xor(v, 2));
                v = fmaxf(v, __shfl_xor(v, 4)); v = fmaxf(v, __shfl_xor(v, 8));
                float mn = fmaxf(mr[mi][r], v*SSC);
                float a  = exp2f(mr[mi][r] - mn);
                mr[mi][r] = mn; lr[mi][r] *= a; al[mi][r] = a;
            }
        const int qrow = wav*32 + (lane>>4)*4;
#pragma unroll
        for (int mi = 0; mi < 2; mi++){
            float rs0 = 0.f, rs1 = 0.f, rs2 = 0.f, rs3 = 0.f;
#pragma unroll
            for (int ni = 0; ni < 4; ni++){
                float p0 = exp2f(sacc[mi][ni][0]*SSC - mr[mi][0]);
                float p1 = exp2f(sacc[mi][ni][1]*SSC - mr[mi][1]);
                float p2 = exp2f(sacc[mi][ni][2]*SSC - mr[mi][2]);
                float p3 = exp2f(sacc[mi][ni][3]*SSC - mr[mi][3]);
                rs0 += p0; rs1 += p1; rs2 += p2; rs3 += p3;
                int col = ni*16 + (lane&15);
                Ps[(qrow + mi*16 + 0)*72 + col] = (half_t)p0;
                Ps[(qrow + mi*16 + 1)*72 + col] = (half_t)p1;
                Ps[(qrow + mi*16 + 2)*72 + col] = (half_t)p2;
                Ps[(qrow + mi*16 + 3)*72 + col] = (half_t)p3;
            }
            float rsv[4] = {rs0, rs1, rs2, rs3};
#pragma unroll
            for (int r = 0; r < 4; r++){
                float v = rsv[r];
                v += __shfl_xor(v, 1); v += __shfl_xor(v, 2);
                v += __shfl_xor(v, 4); v += __shfl_xor(v, 8);
                lr[mi][r] += v;
            }
        }
#pragma unroll
        for (int mi = 0; mi < 2; mi++)
#pragma unroll
            for (int ni = 0; ni < 8; ni++)
#pragma unroll
                for (int r = 0; r < 4; r++)
                    oacc[mi][ni][r] *= al[mi][r];

        // O += P @ V   (reads only this wave's own Ps rows; DS ops in-order per wave)
#pragma unroll
        for (int ks2 = 0; ks2 < 2; ks2++){
            const int kb = ks2*32 + (lane>>4)*8;
            half8 pf[2], vf[8];
#pragma unroll
            for (int mi = 0; mi < 2; mi++) pf[mi] = *(const half8*)(Ps + (wav*32 + mi*16 + (lane&15))*72 + kb);
#pragma unroll
            for (int ni = 0; ni < 8; ni++) vf[ni] = *(const half8*)(Vs + (ni*16 + (lane&15))*64 + kb);
#pragma unroll
            for (int mi = 0; mi < 2; mi++)
#pragma unroll
                for (int ni = 0; ni < 8; ni++)
                    oacc[mi][ni] = MFMA16(pf[mi], vf[ni], oacc[mi][ni]);
        }
    }

    // epilogue: AO[(b*2048+s)][h*128+d] fp16
    const int b = bh >> 4, h = bh & 15;
#pragma unroll
    for (int mi = 0; mi < 2; mi++)
#pragma unroll
        for (int r = 0; r < 4; r++){
            float inv = 1.0f / lr[mi][r];
            int s = qt*128 + wav*32 + mi*16 + (lane>>4)*4 + r;
            size_t rowbase = ((size_t)b*2048 + s)*2048 + h*128;
#pragma unroll
            for (int ni = 0; ni < 8; ni++)
                AO[rowbase + ni*16 + (lane&15)] = (half_t)(oacc[mi][ni][r] * inv);
        }
}

extern "C" void kernel_launch(void* const* d_in, const int* in_sizes, int n_in,
                              void* d_out, int out_size, void* d_ws, size_t ws_size,
                              hipStream_t stream){
    const float* x  = (const float*)d_in[0];
    const float* cs = (const float*)d_in[1];
    const float* sn = (const float*)d_in[2];
    const float* Wq = (const float*)d_in[3];
    const float* Wk = (const float*)d_in[4];
    const float* Wv = (const float*)d_in[5];
    const float* Wo = (const float*)d_in[6];

    half_t* ws = (half_t*)d_ws;
    half_t* xh = ws;                             // 16,777,216 halves (x as fp16)
    half_t* w4 = ws + (size_t)16777216;          // Wq|Wk|Wv|Wo fp16, each 4,194,304
    half_t* qw = ws + (size_t)33554432;          // Q [b,h,s,d]
    half_t* kw = ws + (size_t)50331648;          // K [b,h,s,d]
    half_t* vt = ws + (size_t)67108864;          // V^T [b,h,d,s]
    half_t* ao = ws + (size_t)83886080;          // attn out [(b,s)][h*128+d]

    cvt_k<<<16384, 256, 0, stream>>>(x,  xh,            4194304);
    cvt_k<<<4096,  256, 0, stream>>>(Wq, w4,            1048576);
    cvt_k<<<4096,  256, 0, stream>>>(Wk, w4 + 4194304,  1048576);
    cvt_k<<<4096,  256, 0, stream>>>(Wv, w4 + 8388608,  1048576);
    cvt_k<<<4096,  256, 0, stream>>>(Wo, w4 + 12582912, 1048576);

    gemm_nt<<<dim3(64, 48), 256, 0, stream>>>(xh, w4, qw, kw, vt, nullptr, 0);
    rope_k<<<32768, 256, 0, stream>>>(qw, kw, cs, sn);
    attn_k<<<dim3(16, 64), 256, 0, stream>>>(qw, kw, vt, ao);
    gemm_nt<<<dim3(64, 16), 256, 0, stream>>>(ao, w4 + 12582912, nullptr, nullptr, nullptr,
                                              (float*)d_out, 1);
}

// Round 2
// 802.823 us; speedup vs baseline: 1.3631x; 1.3631x over previous
//
#include <hip/hip_runtime.h>

typedef _Float16 half_t;
typedef __attribute__((ext_vector_type(8))) _Float16 half8;
typedef __attribute__((ext_vector_type(4))) _Float16 half4v;
typedef __attribute__((ext_vector_type(4))) float f32x4;

#define MFMA16(a,b,c) __builtin_amdgcn_mfma_f32_16x16x32_f16((a),(b),(c),0,0,0)

__device__ __forceinline__ void gld_lds16(const half_t* g, half_t* l){
    __builtin_amdgcn_global_load_lds((__attribute__((address_space(1))) void*)(g),
                                     (__attribute__((address_space(3))) void*)(l), 16, 0, 0);
}

// ---------------- fp32 -> fp16 convert ----------------
__global__ __launch_bounds__(256) void cvt_k(const float* __restrict__ s, half_t* __restrict__ d, int n4){
    int i = blockIdx.x * 256 + threadIdx.x;
    if (i < n4){
        float4 v = ((const float4*)s)[i];
        half4v h = { (half_t)v.x, (half_t)v.y, (half_t)v.z, (half_t)v.w };
        ((half4v*)d)[i] = h;
    }
}

// ---------------- NT GEMM: C[m,n] = sum_k A[m,k]*B[n,k] ----------------
__global__ __launch_bounds__(256) void gemm_nt(const half_t* __restrict__ A, const half_t* __restrict__ B,
                                               half_t* __restrict__ Qw, half_t* __restrict__ Kw,
                                               half_t* __restrict__ Vt, float* __restrict__ Co, int kind){
    const int tid  = threadIdx.x;
    const int lane = tid & 63;
    const int wav  = tid >> 6;
    const int wm   = (wav >> 1) * 64;
    const int wn   = (wav & 1) * 64;
    const int bm   = blockIdx.x;
    const int bn   = blockIdx.y;
    const int KD   = 2048;

    __shared__ __align__(16) half_t As[128*64];
    __shared__ __align__(16) half_t Bs[128*64];

    f32x4 acc[4][4] = {};

    const half_t* Ab = A + (size_t)bm * 128 * KD;
    const half_t* Bb = B + (size_t)bn * 128 * KD;

    for (int k0 = 0; k0 < KD; k0 += 64){
#pragma unroll
        for (int i = 0; i < 4; i++){
            int c = tid + i*256;
            gld_lds16(Ab + (size_t)(c>>3)*KD + k0 + (c&7)*8, As + c*8);
        }
#pragma unroll
        for (int i = 0; i < 4; i++){
            int c = tid + i*256;
            gld_lds16(Bb + (size_t)(c>>3)*KD + k0 + (c&7)*8, Bs + c*8);
        }
        __syncthreads();
#pragma unroll
        for (int ks = 0; ks < 2; ks++){
            const int kb = ks*32 + (lane>>4)*8;
            half8 af[4], bf[4];
#pragma unroll
            for (int mi = 0; mi < 4; mi++) af[mi] = *(const half8*)(As + (wm + mi*16 + (lane&15))*64 + kb);
#pragma unroll
            for (int ni = 0; ni < 4; ni++) bf[ni] = *(const half8*)(Bs + (wn + ni*16 + (lane&15))*64 + kb);
#pragma unroll
            for (int mi = 0; mi < 4; mi++)
#pragma unroll
                for (int ni = 0; ni < 4; ni++)
                    acc[mi][ni] = MFMA16(af[mi], bf[ni], acc[mi][ni]);
        }
        __syncthreads();
    }

    const int rbase = wm + (lane>>4)*4;
    const int cbase = wn + (lane&15);

    if (kind == 0){
        const int which = bn >> 4;
        const int nb = (bn & 15) * 128;
        if (which < 2){
            half_t* dst = which ? Kw : Qw;
#pragma unroll
            for (int mi = 0; mi < 4; mi++)
#pragma unroll
                for (int ni = 0; ni < 4; ni++)
#pragma unroll
                    for (int r = 0; r < 4; r++){
                        int m = bm*128 + rbase + mi*16 + r;
                        int n = nb + cbase + ni*16;
                        dst[(((size_t)(m>>11)*16 + (n>>7))*2048 + (m&2047))*128 + (n&127)] = (half_t)acc[mi][ni][r];
                    }
        } else {
#pragma unroll
            for (int mi = 0; mi < 4; mi++)
#pragma unroll
                for (int ni = 0; ni < 4; ni++){
                    int m0 = bm*128 + rbase + mi*16;
                    int n  = nb + cbase + ni*16;
                    half4v h = {(half_t)acc[mi][ni][0], (half_t)acc[mi][ni][1],
                                (half_t)acc[mi][ni][2], (half_t)acc[mi][ni][3]};
                    *(half4v*)(Vt + (((size_t)(m0>>11)*16 + (n>>7))*128 + (n&127))*2048 + (m0&2047)) = h;
                }
        }
    } else {
#pragma unroll
        for (int mi = 0; mi < 4; mi++)
#pragma unroll
            for (int ni = 0; ni < 4; ni++)
#pragma unroll
                for (int r = 0; r < 4; r++){
                    int m = bm*128 + rbase + mi*16 + r;
                    int n = bn*128 + cbase + ni*16;
                    Co[(size_t)m*2048 + n] = acc[mi][ni][r];
                }
    }
}

// ---------------- RoPE in-place ----------------
__global__ __launch_bounds__(256) void rope_k(half_t* __restrict__ Qw, half_t* __restrict__ Kw,
                                              const float* __restrict__ cs, const float* __restrict__ sn){
    int t  = blockIdx.x * 256 + threadIdx.x;
    int d  = t & 63;
    int s  = (t >> 6) & 2047;
    int bh = t >> 17;
    float c  = cs[s*64 + d];
    float si = sn[s*64 + d];
    size_t base = ((size_t)bh*2048 + s)*128 + d;
    float q1 = (float)Qw[base], q2 = (float)Qw[base+64];
    Qw[base]    = (half_t)(q1*c - q2*si);
    Qw[base+64] = (half_t)(q1*si + q2*c);
    float k1 = (float)Kw[base], k2 = (float)Kw[base+64];
    Kw[base]    = (half_t)(k1*c - k2*si);
    Kw[base+64] = (half_t)(k1*si + k2*c);
}

// ---------------- Flash attention, S^T formulation ----------------
// Q[bh][s][128], K[bh][s][128], Vt[bh][128][s] -> AO[(b,s)][h*128+d]
// Per block: 128 q (4 waves x 32 q). Per kt: 64 keys.
// S^T = MFMA(Kfrag, Qfrag): rows=key, cols=q(lane&15) -> per-lane softmax state.
// XOR-swizzled Ks/Vs (global-address side of global_load_lds) for conflict-free frag reads.
__global__ __launch_bounds__(256) void attn_k(const half_t* __restrict__ Q, const half_t* __restrict__ K,
                                              const half_t* __restrict__ Vt, half_t* __restrict__ AO){
    const int tid  = threadIdx.x;
    const int lane = tid & 63;
    const int w    = lane >> 4;
    const int l15  = lane & 15;
    const int l7   = lane & 7;
    const int wav  = tid >> 6;
    const int qt   = blockIdx.x;   // 16 q-tiles of 128
    const int bh   = blockIdx.y;   // 64

    // Ks: 64x128 (16KB) | Vs: 128x64 (16KB) | Ps: per-wave 32x80 (20KB). Obuf reuses Ks+Vs.
    __shared__ __align__(16) half_t smem[8192 + 8192 + 4*2560];
    half_t* Ks = smem;
    half_t* Vs = smem + 8192;
    half_t* Ps = smem + 16384 + wav*2560;
    half_t* Ob = smem + wav*4096;

    // Q fragments (held across K loop); same register image serves as MFMA B-operand.
    const half_t* Qb = Q + ((size_t)bh*2048 + qt*128 + wav*32)*128;
    half8 aq[2][4];
#pragma unroll
    for (int qi = 0; qi < 2; qi++)
#pragma unroll
        for (int ks = 0; ks < 4; ks++)
            aq[qi][ks] = *(const half8*)(Qb + (qi*16 + l15)*128 + ks*32 + w*8);

    f32x4 oacc[8][2] = {};          // O^T: 8 d-tiles x 2 q-tiles
    float m_[2] = {-1e30f, -1e30f};
    float l_[2] = {0.0f, 0.0f};

    const float SSC = 0.08838834764831845f * 1.4426950408889634f;  // 1/sqrt(128) * log2(e)

    for (int kt = 0; kt < 32; kt++){
        const half_t* Kb = K  + ((size_t)bh*2048 + kt*64)*128;
        const half_t* Vb = Vt + (size_t)bh*128*2048 + kt*64;
        __syncthreads();
        // stage K tile [64 key][128 d], chunk-of-8 xor-swizzled: phys pc holds logical pc^(key&7)
#pragma unroll
        for (int i = 0; i < 4; i++){
            int c = tid + i*256;
            int key = c >> 4, pc = c & 15;
            gld_lds16(Kb + key*128 + ((pc ^ (key&7)) << 3), Ks + c*8);
        }
        // stage V tile [128 d][64 key], phys pc holds logical pc^(d&7)
#pragma unroll
        for (int i = 0; i < 4; i++){
            int c = tid + i*256;
            int d = c >> 3, pc = c & 7;
            gld_lds16(Vb + (size_t)d*2048 + ((pc ^ (d&7)) << 3), Vs + c*8);
        }
        __syncthreads();

        // S^T = K @ Q^T : rows=key (4 tiles), cols=q (2 tiles)
        f32x4 sacc[4][2] = {};
#pragma unroll
        for (int ks = 0; ks < 4; ks++){
            half8 kf[4];
#pragma unroll
            for (int t = 0; t < 4; t++){
                int key = t*16 + l15;
                kf[t] = *(const half8*)(Ks + key*128 + (((ks*4 + w) ^ l7) << 3));
            }
#pragma unroll
            for (int t = 0; t < 4; t++)
#pragma unroll
                for (int qi = 0; qi < 2; qi++)
                    sacc[t][qi] = MFMA16(kf[t], aq[qi][ks], sacc[t][qi]);
        }

        // online softmax per q-column (per-lane state, replicated across quads)
#pragma unroll
        for (int qi = 0; qi < 2; qi++){
            float mx = sacc[0][qi][0];
#pragma unroll
            for (int t = 0; t < 4; t++)
#pragma unroll
                for (int r = 0; r < 4; r++) mx = fmaxf(mx, sacc[t][qi][r]);
            mx = fmaxf(mx, __shfl_xor(mx, 16));
            mx = fmaxf(mx, __shfl_xor(mx, 32));
            float mn = fmaxf(m_[qi], mx*SSC);
            float alpha = exp2f(m_[qi] - mn);
            m_[qi] = mn;
            float sum = 0.0f;
#pragma unroll
            for (int t = 0; t < 4; t++){
                float p0 = exp2f(sacc[t][qi][0]*SSC - mn);
                float p1 = exp2f(sacc[t][qi][1]*SSC - mn);
                float p2 = exp2f(sacc[t][qi][2]*SSC - mn);
                float p3 = exp2f(sacc[t][qi][3]*SSC - mn);
                sum += (p0 + p1) + (p2 + p3);
                half4v h = {(half_t)p0, (half_t)p1, (half_t)p2, (half_t)p3};
                *(half4v*)(Ps + (qi*16 + l15)*80 + t*16 + w*4) = h;   // P[q][key], per-wave region
            }
            sum += __shfl_xor(sum, 16);
            sum += __shfl_xor(sum, 32);
            l_[qi] = l_[qi]*alpha + sum;
#pragma unroll
            for (int t = 0; t < 8; t++)
#pragma unroll
                for (int r = 0; r < 4; r++) oacc[t][qi][r] *= alpha;
        }

        // O^T += V^T @ P^T  (A = V^T frag from Vs, B = P rows from Ps; per-wave, in-order DS)
#pragma unroll
        for (int c2 = 0; c2 < 2; c2++){
            half8 vf[8], pf[2];
#pragma unroll
            for (int t = 0; t < 8; t++){
                int d = t*16 + l15;
                vf[t] = *(const half8*)(Vs + d*64 + (((c2*4 + w) ^ l7) << 3));
            }
#pragma unroll
            for (int qi = 0; qi < 2; qi++)
                pf[qi] = *(const half8*)(Ps + (qi*16 + l15)*80 + c2*32 + w*8);
#pragma unroll
            for (int t = 0; t < 8; t++)
#pragma unroll
                for (int qi = 0; qi < 2; qi++)
                    oacc[t][qi] = MFMA16(vf[t], pf[qi], oacc[t][qi]);
        }
    }

    // epilogue: transpose O^T -> O through LDS (reuse Ks/Vs space), coalesced global stores
    float inv[2] = {1.0f / l_[0], 1.0f / l_[1]};
    __syncthreads();   // all waves done with Ks/Vs
#pragma unroll
    for (int t = 0; t < 8; t++)
#pragma unroll
        for (int qi = 0; qi < 2; qi++){
            int q  = qi*16 + l15;               // row in Ob
            int c8 = t*2 + (w>>1);              // logical d-chunk
            int pc = c8 ^ l7;                   // q&7 == l7
            half4v h = {(half_t)(oacc[t][qi][0]*inv[qi]), (half_t)(oacc[t][qi][1]*inv[qi]),
                        (half_t)(oacc[t][qi][2]*inv[qi]), (half_t)(oacc[t][qi][3]*inv[qi])};
            *(half4v*)(Ob + q*128 + pc*8 + (w&1)*4) = h;
        }
    const int b = bh >> 4, h = bh & 15;
#pragma unroll
    for (int it = 0; it < 8; it++){
        int q  = it*4 + w;
        half8 rd = *(const half8*)(Ob + q*128 + ((l15 ^ (q&7)) << 3));
        int s = qt*128 + wav*32 + q;
        *(half8*)(AO + ((size_t)b*2048 + s)*2048 + h*128 + l15*8) = rd;
    }
}

extern "C" void kernel_launch(void* const* d_in, const int* in_sizes, int n_in,
                              void* d_out, int out_size, void* d_ws, size_t ws_size,
                              hipStream_t stream){
    const float* x  = (const float*)d_in[0];
    const float* cs = (const float*)d_in[1];
    const float* sn = (const float*)d_in[2];
    const float* Wq = (const float*)d_in[3];
    const float* Wk = (const float*)d_in[4];
    const float* Wv = (const float*)d_in[5];
    const float* Wo = (const float*)d_in[6];

    half_t* ws = (half_t*)d_ws;
    half_t* xh = ws;
    half_t* w4 = ws + (size_t)16777216;
    half_t* qw = ws + (size_t)33554432;
    half_t* kw = ws + (size_t)50331648;
    half_t* vt = ws + (size_t)67108864;
    half_t* ao = ws + (size_t)83886080;

    cvt_k<<<16384, 256, 0, stream>>>(x,  xh,            4194304);
    cvt_k<<<4096,  256, 0, stream>>>(Wq, w4,            1048576);
    cvt_k<<<4096,  256, 0, stream>>>(Wk, w4 + 4194304,  1048576);
    cvt_k<<<4096,  256, 0, stream>>>(Wv, w4 + 8388608,  1048576);
    cvt_k<<<4096,  256, 0, stream>>>(Wo, w4 + 12582912, 1048576);

    gemm_nt<<<dim3(64, 48), 256, 0, stream>>>(xh, w4, qw, kw, vt, nullptr, 0);
    rope_k<<<32768, 256, 0, stream>>>(qw, kw, cs, sn);
    attn_k<<<dim3(16, 64), 256, 0, stream>>>(qw, kw, vt, ao);
    gemm_nt<<<dim3(64, 16), 256, 0, stream>>>(ao, w4 + 12582912, nullptr, nullptr, nullptr,
                                              (float*)d_out, 1);
}